// Round 2
// baseline (8571.857 us; speedup 1.0000x reference)
//
#include <hip/hip_runtime.h>

#define KDIM 512
#define TDIM 64
#define BDIM 256
#define NWAVE 16
#define BLOCK 1024
#define LOG2E 1.4426950408889634f

// ---- prep: fold LOG2E into coeff/bias once per launch (runs in ~2 us) ----
__global__ __launch_bounds__(256) void prefold_kernel(
    const float* __restrict__ coeff, const float* __restrict__ bias,
    float* __restrict__ c2, float* __restrict__ b2)
{
    const int i = blockIdx.x * 256 + threadIdx.x;   // float4 index, KDIM*KDIM/4 total
    const float4 c = ((const float4*)coeff)[i];
    const float4 b = ((const float4*)bias)[i];
    ((float4*)c2)[i] = make_float4(c.x * LOG2E, c.y * LOG2E, c.z * LOG2E, c.w * LOG2E);
    ((float4*)b2)[i] = make_float4(b.x * LOG2E, b.y * LOG2E, b.z * LOG2E, b.w * LOG2E);
}

__device__ __forceinline__ float wave_reduce_sum(float v) {
    #pragma unroll
    for (int off = 1; off < 64; off <<= 1)
        v += __shfl_xor(v, off, 64);
    return v;
}

// One workgroup per batch element; whole T-recurrence inside the kernel.
// FOLDED=true: cc/bb are coeff*LOG2E, bias*LOG2E (from d_ws).
template <bool FOLDED>
__global__ __launch_bounds__(BLOCK, 4) void hmm_forward_kernel(
    const float* __restrict__ x,           // [B, T]
    const float* __restrict__ prior_w,     // [K]
    const float* __restrict__ emission_w,  // [K, 2]
    const float* __restrict__ cc,          // [K, K]
    const float* __restrict__ bb,          // [K, K]
    float* __restrict__ out)               // [B, K]
{
    __shared__ float post[KDIM];
    __shared__ float em0s[KDIM];
    __shared__ float emds[KDIM];          // em1 - em0
    __shared__ float part[NWAVE][KDIM];   // per-wave pbe partials (32 KB)
    __shared__ float rtmp[NWAVE];
    __shared__ float xs[TDIM];

    const int b    = blockIdx.x;
    const int tid  = threadIdx.x;
    const int lane = tid & 63;
    const int wv   = tid >> 6;
    const int k0   = 4 * lane;            // lane covers k0..k0+3 and k0+256..k0+259

    if (tid < TDIM) xs[tid] = x[b * TDIM + tid];
    if (tid < KDIM) {
        const float w0 = emission_w[2 * tid + 0];
        const float w1 = emission_w[2 * tid + 1];
        const float e0 = 1.0f / (1.0f + exp2f((w1 - w0) * LOG2E));
        em0s[tid] = e0;
        emds[tid] = 1.0f - 2.0f * e0;     // (1-e0) - e0
    }
    __syncthreads();

    // ---- t = 0: post0 = normalize(exp(prior_w) * evidence(x0)) ----
    {
        const float x0 = xs[0];
        float v = 0.0f;
        if (tid < KDIM) {
            const float pr = exp2f(prior_w[tid] * LOG2E);
            const float e  = fmaf(x0, emds[tid], em0s[tid]);
            v = pr * e;
        }
        float s = wave_reduce_sum(v);
        if (lane == 0) rtmp[wv] = s;
        __syncthreads();
        if (wv == 0) {
            float t2 = (lane < NWAVE) ? rtmp[lane] : 0.0f;
            #pragma unroll
            for (int off = 1; off < NWAVE; off <<= 1)
                t2 += __shfl_xor(t2, off, 64);
            if (lane == 0) rtmp[0] = t2;
        }
        __syncthreads();
        const float rn = __builtin_amdgcn_rcpf(rtmp[0]);
        if (tid < KDIM) post[tid] = v * rn;
        __syncthreads();
    }

    // ---- steps t = 1 .. T-1 ----
    for (int t = 1; t < TDIM; ++t) {
        float acc[8];
        #pragma unroll
        for (int i = 0; i < 8; ++i) acc[i] = 0.0f;

        // Wave wv handles rows j = wv + 16*m (m=0..31), processed as pairs
        // (jA = wv + 32*i, jB = jA + 16), i = 0..15, with next-pair prefetch.
        const float* cA = cc + (size_t)wv * KDIM + k0;
        const float* bA = bb + (size_t)wv * KDIM + k0;
        const float* cB = cA + 16 * KDIM;
        const float* bB = bA + 16 * KDIM;

        float4 cA0 = *(const float4*)cA;
        float4 cA1 = *(const float4*)(cA + 256);
        float4 bA0 = *(const float4*)bA;
        float4 bA1 = *(const float4*)(bA + 256);
        float4 cB0 = *(const float4*)cB;
        float4 cB1 = *(const float4*)(cB + 256);
        float4 bB0 = *(const float4*)bB;
        float4 bB1 = *(const float4*)(bB + 256);

        #pragma unroll
        for (int i = 0; i < 16; ++i) {
            // prefetch next row pair (clamped on last iter: reload same rows, L1-hot)
            const int adv = (i < 15) ? 32 * KDIM : 0;
            cA += adv; bA += adv; cB += adv; bB += adv;
            const float4 nA0 = *(const float4*)cA;
            const float4 nA1 = *(const float4*)(cA + 256);
            const float4 mA0 = *(const float4*)bA;
            const float4 mA1 = *(const float4*)(bA + 256);
            const float4 nB0 = *(const float4*)cB;
            const float4 nB1 = *(const float4*)(cB + 256);
            const float4 mB0 = *(const float4*)bB;
            const float4 mB1 = *(const float4*)(bB + 256);

            const float pA  = post[wv + 32 * i];
            const float pB  = post[wv + 16 + 32 * i];
            const float pAe = FOLDED ? pA : pA * LOG2E;
            const float pBe = FOLDED ? pB : pB * LOG2E;

            float eA0, eA1, eA2, eA3, eA4, eA5, eA6, eA7;
            float eB0, eB1, eB2, eB3, eB4, eB5, eB6, eB7;
            if (FOLDED) {
                eA0 = exp2f(fmaf(pAe, cA0.x, bA0.x));
                eA1 = exp2f(fmaf(pAe, cA0.y, bA0.y));
                eA2 = exp2f(fmaf(pAe, cA0.z, bA0.z));
                eA3 = exp2f(fmaf(pAe, cA0.w, bA0.w));
                eA4 = exp2f(fmaf(pAe, cA1.x, bA1.x));
                eA5 = exp2f(fmaf(pAe, cA1.y, bA1.y));
                eA6 = exp2f(fmaf(pAe, cA1.z, bA1.z));
                eA7 = exp2f(fmaf(pAe, cA1.w, bA1.w));
                eB0 = exp2f(fmaf(pBe, cB0.x, bB0.x));
                eB1 = exp2f(fmaf(pBe, cB0.y, bB0.y));
                eB2 = exp2f(fmaf(pBe, cB0.z, bB0.z));
                eB3 = exp2f(fmaf(pBe, cB0.w, bB0.w));
                eB4 = exp2f(fmaf(pBe, cB1.x, bB1.x));
                eB5 = exp2f(fmaf(pBe, cB1.y, bB1.y));
                eB6 = exp2f(fmaf(pBe, cB1.z, bB1.z));
                eB7 = exp2f(fmaf(pBe, cB1.w, bB1.w));
            } else {
                eA0 = exp2f(fmaf(pAe, cA0.x, bA0.x * LOG2E));
                eA1 = exp2f(fmaf(pAe, cA0.y, bA0.y * LOG2E));
                eA2 = exp2f(fmaf(pAe, cA0.z, bA0.z * LOG2E));
                eA3 = exp2f(fmaf(pAe, cA0.w, bA0.w * LOG2E));
                eA4 = exp2f(fmaf(pAe, cA1.x, bA1.x * LOG2E));
                eA5 = exp2f(fmaf(pAe, cA1.y, bA1.y * LOG2E));
                eA6 = exp2f(fmaf(pAe, cA1.z, bA1.z * LOG2E));
                eA7 = exp2f(fmaf(pAe, cA1.w, bA1.w * LOG2E));
                eB0 = exp2f(fmaf(pBe, cB0.x, bB0.x * LOG2E));
                eB1 = exp2f(fmaf(pBe, cB0.y, bB0.y * LOG2E));
                eB2 = exp2f(fmaf(pBe, cB0.z, bB0.z * LOG2E));
                eB3 = exp2f(fmaf(pBe, cB0.w, bB0.w * LOG2E));
                eB4 = exp2f(fmaf(pBe, cB1.x, bB1.x * LOG2E));
                eB5 = exp2f(fmaf(pBe, cB1.y, bB1.y * LOG2E));
                eB6 = exp2f(fmaf(pBe, cB1.z, bB1.z * LOG2E));
                eB7 = exp2f(fmaf(pBe, cB1.w, bB1.w * LOG2E));
            }

            float sA = ((eA0 + eA1) + (eA2 + eA3)) + ((eA4 + eA5) + (eA6 + eA7));
            float sB = ((eB0 + eB1) + (eB2 + eB3)) + ((eB4 + eB5) + (eB6 + eB7));
            // two independent butterfly chains, interleaved for latency hiding
            #pragma unroll
            for (int off = 1; off < 64; off <<= 1) {
                sA += __shfl_xor(sA, off, 64);
                sB += __shfl_xor(sB, off, 64);
            }
            const float scA = pA * __builtin_amdgcn_rcpf(sA);
            const float scB = pB * __builtin_amdgcn_rcpf(sB);

            acc[0] = fmaf(scA, eA0, acc[0]); acc[0] = fmaf(scB, eB0, acc[0]);
            acc[1] = fmaf(scA, eA1, acc[1]); acc[1] = fmaf(scB, eB1, acc[1]);
            acc[2] = fmaf(scA, eA2, acc[2]); acc[2] = fmaf(scB, eB2, acc[2]);
            acc[3] = fmaf(scA, eA3, acc[3]); acc[3] = fmaf(scB, eB3, acc[3]);
            acc[4] = fmaf(scA, eA4, acc[4]); acc[4] = fmaf(scB, eB4, acc[4]);
            acc[5] = fmaf(scA, eA5, acc[5]); acc[5] = fmaf(scB, eB5, acc[5]);
            acc[6] = fmaf(scA, eA6, acc[6]); acc[6] = fmaf(scB, eB6, acc[6]);
            acc[7] = fmaf(scA, eA7, acc[7]); acc[7] = fmaf(scB, eB7, acc[7]);

            cA0 = nA0; cA1 = nA1; bA0 = mA0; bA1 = mA1;
            cB0 = nB0; cB1 = nB1; bB0 = mB0; bB1 = mB1;
        }

        *(float4*)(&part[wv][k0])       = make_float4(acc[0], acc[1], acc[2], acc[3]);
        *(float4*)(&part[wv][256 + k0]) = make_float4(acc[4], acc[5], acc[6], acc[7]);
        __syncthreads();

        float v = 0.0f;
        if (tid < KDIM) {
            float pbe = 0.0f;
            #pragma unroll
            for (int w2 = 0; w2 < NWAVE; ++w2) pbe += part[w2][tid];
            const float xt = xs[t];
            v = pbe * fmaf(xt, emds[tid], em0s[tid]);
        }
        float s = wave_reduce_sum(v);
        if (lane == 0) rtmp[wv] = s;
        __syncthreads();
        if (wv == 0) {
            float t2 = (lane < NWAVE) ? rtmp[lane] : 0.0f;
            #pragma unroll
            for (int off = 1; off < NWAVE; off <<= 1)
                t2 += __shfl_xor(t2, off, 64);
            if (lane == 0) rtmp[0] = t2;
        }
        __syncthreads();
        const float rn = __builtin_amdgcn_rcpf(rtmp[0]);
        if (tid < KDIM) post[tid] = v * rn;
        __syncthreads();
    }

    if (tid < KDIM) out[b * KDIM + tid] = post[tid];
}

extern "C" void kernel_launch(void* const* d_in, const int* in_sizes, int n_in,
                              void* d_out, int out_size, void* d_ws, size_t ws_size,
                              hipStream_t stream) {
    const float* x          = (const float*)d_in[0];
    const float* prior_w    = (const float*)d_in[1];
    const float* emission_w = (const float*)d_in[2];
    const float* coeff      = (const float*)d_in[3];
    const float* bias       = (const float*)d_in[4];
    float* out              = (float*)d_out;

    const size_t need = (size_t)2 * KDIM * KDIM * sizeof(float);
    if (ws_size >= need) {
        float* c2 = (float*)d_ws;
        float* b2 = c2 + (size_t)KDIM * KDIM;
        hipLaunchKernelGGL(prefold_kernel, dim3(KDIM * KDIM / 4 / 256), dim3(256),
                           0, stream, coeff, bias, c2, b2);
        hipLaunchKernelGGL((hmm_forward_kernel<true>), dim3(BDIM), dim3(BLOCK),
                           0, stream, x, prior_w, emission_w, c2, b2, out);
    } else {
        hipLaunchKernelGGL((hmm_forward_kernel<false>), dim3(BDIM), dim3(BLOCK),
                           0, stream, x, prior_w, emission_w, coeff, bias, out);
    }
}

// Round 3
// 8565.694 us; speedup vs baseline: 1.0007x; 1.0007x over previous
//
#include <hip/hip_runtime.h>

#define KDIM 512
#define TDIM 64
#define BDIM 256
#define NWAVE 16
#define BLOCK 1024
#define LOG2E 1.4426950408889634f

__device__ __forceinline__ float fast_exp2(float v) { return __builtin_amdgcn_exp2f(v); }

__device__ __forceinline__ float wave_reduce_sum(float v) {
    #pragma unroll
    for (int off = 1; off < 64; off <<= 1)
        v += __shfl_xor(v, off, 64);
    return v;
}

// One workgroup per batch element; whole T-recurrence inside the kernel.
// coeff/bias are read DIRECTLY from d_in (cached L2-resident; d_ws reads
// proved uncached in R2 -> 17.5 GB HBM fetch. Never stage hot data there.)
__global__ __launch_bounds__(BLOCK, 4) void hmm_forward_kernel(
    const float* __restrict__ x,           // [B, T]
    const float* __restrict__ prior_w,     // [K]
    const float* __restrict__ emission_w,  // [K, 2]
    const float* __restrict__ coeff,       // [K, K]
    const float* __restrict__ bias,        // [K, K]
    float* __restrict__ out)               // [B, K]
{
    __shared__ float post[KDIM];
    __shared__ float em0s[KDIM];
    __shared__ float emds[KDIM];          // em1 - em0
    __shared__ float part[NWAVE][KDIM];   // per-wave pbe partials (32 KB)
    __shared__ float rtmp[NWAVE];
    __shared__ float xs[TDIM];

    const int b    = blockIdx.x;
    const int tid  = threadIdx.x;
    const int lane = tid & 63;
    const int wv   = tid >> 6;
    const int k0   = 4 * lane;            // lane covers k0..k0+3 and k0+256..k0+259

    if (tid < TDIM) xs[tid] = x[b * TDIM + tid];
    if (tid < KDIM) {
        const float w0 = emission_w[2 * tid + 0];
        const float w1 = emission_w[2 * tid + 1];
        const float e0 = 1.0f / (1.0f + fast_exp2((w1 - w0) * LOG2E));
        em0s[tid] = e0;
        emds[tid] = 1.0f - 2.0f * e0;     // (1-e0) - e0
    }
    __syncthreads();

    // ---- t = 0: post0 = normalize(exp(prior_w) * evidence(x0)) ----
    {
        const float x0 = xs[0];
        float v = 0.0f;
        if (tid < KDIM) {
            const float pr = fast_exp2(prior_w[tid] * LOG2E);
            const float e  = fmaf(x0, emds[tid], em0s[tid]);
            v = pr * e;
        }
        float s = wave_reduce_sum(v);
        if (lane == 0) rtmp[wv] = s;
        __syncthreads();
        if (wv == 0) {
            float t2 = (lane < NWAVE) ? rtmp[lane] : 0.0f;
            #pragma unroll
            for (int off = 1; off < NWAVE; off <<= 1)
                t2 += __shfl_xor(t2, off, 64);
            if (lane == 0) rtmp[0] = t2;
        }
        __syncthreads();
        const float rn = __builtin_amdgcn_rcpf(rtmp[0]);
        if (tid < KDIM) post[tid] = v * rn;
        __syncthreads();
    }

    // ---- steps t = 1 .. T-1 ----
    for (int t = 1; t < TDIM; ++t) {
        float acc[8];
        #pragma unroll
        for (int i = 0; i < 8; ++i) acc[i] = 0.0f;

        // Wave wv handles rows j = wv + 16*m (m=0..31), processed as pairs
        // (jA = wv + 32*i, jB = jA + 16), i = 0..15, with next-pair prefetch.
        const float* cA = coeff + (size_t)wv * KDIM + k0;
        const float* bA = bias  + (size_t)wv * KDIM + k0;
        const float* cB = cA + 16 * KDIM;
        const float* bB = bA + 16 * KDIM;

        float4 cA0 = *(const float4*)cA;
        float4 cA1 = *(const float4*)(cA + 256);
        float4 bA0 = *(const float4*)bA;
        float4 bA1 = *(const float4*)(bA + 256);
        float4 cB0 = *(const float4*)cB;
        float4 cB1 = *(const float4*)(cB + 256);
        float4 bB0 = *(const float4*)bB;
        float4 bB1 = *(const float4*)(bB + 256);

        #pragma unroll
        for (int i = 0; i < 16; ++i) {
            // prefetch next row pair (clamped on last iter: reload same rows, L1-hot)
            const int adv = (i < 15) ? 32 * KDIM : 0;
            cA += adv; bA += adv; cB += adv; bB += adv;
            const float4 nA0 = *(const float4*)cA;
            const float4 nA1 = *(const float4*)(cA + 256);
            const float4 mA0 = *(const float4*)bA;
            const float4 mA1 = *(const float4*)(bA + 256);
            const float4 nB0 = *(const float4*)cB;
            const float4 nB1 = *(const float4*)(cB + 256);
            const float4 mB0 = *(const float4*)bB;
            const float4 mB1 = *(const float4*)(bB + 256);

            const float pA = post[wv + 32 * i];
            const float pB = post[wv + 16 + 32 * i];

            const float eA0 = fast_exp2(fmaf(pA, cA0.x, bA0.x) * LOG2E);
            const float eA1 = fast_exp2(fmaf(pA, cA0.y, bA0.y) * LOG2E);
            const float eA2 = fast_exp2(fmaf(pA, cA0.z, bA0.z) * LOG2E);
            const float eA3 = fast_exp2(fmaf(pA, cA0.w, bA0.w) * LOG2E);
            const float eA4 = fast_exp2(fmaf(pA, cA1.x, bA1.x) * LOG2E);
            const float eA5 = fast_exp2(fmaf(pA, cA1.y, bA1.y) * LOG2E);
            const float eA6 = fast_exp2(fmaf(pA, cA1.z, bA1.z) * LOG2E);
            const float eA7 = fast_exp2(fmaf(pA, cA1.w, bA1.w) * LOG2E);
            const float eB0 = fast_exp2(fmaf(pB, cB0.x, bB0.x) * LOG2E);
            const float eB1 = fast_exp2(fmaf(pB, cB0.y, bB0.y) * LOG2E);
            const float eB2 = fast_exp2(fmaf(pB, cB0.z, bB0.z) * LOG2E);
            const float eB3 = fast_exp2(fmaf(pB, cB0.w, bB0.w) * LOG2E);
            const float eB4 = fast_exp2(fmaf(pB, cB1.x, bB1.x) * LOG2E);
            const float eB5 = fast_exp2(fmaf(pB, cB1.y, bB1.y) * LOG2E);
            const float eB6 = fast_exp2(fmaf(pB, cB1.z, bB1.z) * LOG2E);
            const float eB7 = fast_exp2(fmaf(pB, cB1.w, bB1.w) * LOG2E);

            float sA = ((eA0 + eA1) + (eA2 + eA3)) + ((eA4 + eA5) + (eA6 + eA7));
            float sB = ((eB0 + eB1) + (eB2 + eB3)) + ((eB4 + eB5) + (eB6 + eB7));
            // two independent butterfly chains, interleaved for latency hiding
            #pragma unroll
            for (int off = 1; off < 64; off <<= 1) {
                sA += __shfl_xor(sA, off, 64);
                sB += __shfl_xor(sB, off, 64);
            }
            const float scA = pA * __builtin_amdgcn_rcpf(sA);
            const float scB = pB * __builtin_amdgcn_rcpf(sB);

            acc[0] = fmaf(scA, eA0, acc[0]); acc[0] = fmaf(scB, eB0, acc[0]);
            acc[1] = fmaf(scA, eA1, acc[1]); acc[1] = fmaf(scB, eB1, acc[1]);
            acc[2] = fmaf(scA, eA2, acc[2]); acc[2] = fmaf(scB, eB2, acc[2]);
            acc[3] = fmaf(scA, eA3, acc[3]); acc[3] = fmaf(scB, eB3, acc[3]);
            acc[4] = fmaf(scA, eA4, acc[4]); acc[4] = fmaf(scB, eB4, acc[4]);
            acc[5] = fmaf(scA, eA5, acc[5]); acc[5] = fmaf(scB, eB5, acc[5]);
            acc[6] = fmaf(scA, eA6, acc[6]); acc[6] = fmaf(scB, eB6, acc[6]);
            acc[7] = fmaf(scA, eA7, acc[7]); acc[7] = fmaf(scB, eB7, acc[7]);

            cA0 = nA0; cA1 = nA1; bA0 = mA0; bA1 = mA1;
            cB0 = nB0; cB1 = nB1; bB0 = mB0; bB1 = mB1;
        }

        *(float4*)(&part[wv][k0])       = make_float4(acc[0], acc[1], acc[2], acc[3]);
        *(float4*)(&part[wv][256 + k0]) = make_float4(acc[4], acc[5], acc[6], acc[7]);
        __syncthreads();

        float v = 0.0f;
        if (tid < KDIM) {
            float pbe = 0.0f;
            #pragma unroll
            for (int w2 = 0; w2 < NWAVE; ++w2) pbe += part[w2][tid];
            const float xt = xs[t];
            v = pbe * fmaf(xt, emds[tid], em0s[tid]);
        }
        float s = wave_reduce_sum(v);
        if (lane == 0) rtmp[wv] = s;
        __syncthreads();
        if (wv == 0) {
            float t2 = (lane < NWAVE) ? rtmp[lane] : 0.0f;
            #pragma unroll
            for (int off = 1; off < NWAVE; off <<= 1)
                t2 += __shfl_xor(t2, off, 64);
            if (lane == 0) rtmp[0] = t2;
        }
        __syncthreads();
        const float rn = __builtin_amdgcn_rcpf(rtmp[0]);
        if (tid < KDIM) post[tid] = v * rn;
        __syncthreads();
    }

    if (tid < KDIM) out[b * KDIM + tid] = post[tid];
}

extern "C" void kernel_launch(void* const* d_in, const int* in_sizes, int n_in,
                              void* d_out, int out_size, void* d_ws, size_t ws_size,
                              hipStream_t stream) {
    const float* x          = (const float*)d_in[0];
    const float* prior_w    = (const float*)d_in[1];
    const float* emission_w = (const float*)d_in[2];
    const float* coeff      = (const float*)d_in[3];
    const float* bias       = (const float*)d_in[4];
    float* out              = (float*)d_out;

    hipLaunchKernelGGL(hmm_forward_kernel, dim3(BDIM), dim3(BLOCK), 0, stream,
                       x, prior_w, emission_w, coeff, bias, out);
}

// Round 4
// 1199.189 us; speedup vs baseline: 7.1480x; 7.1429x over previous
//
#include <hip/hip_runtime.h>

#define KDIM 512
#define TDIM 64
#define BDIM 256
#define NWAVE 16
#define BLOCK 1024
#define LOG2E 1.4426950408889634f

__device__ __forceinline__ float fast_exp2(float v) { return __builtin_amdgcn_exp2f(v); }
__device__ __forceinline__ float fast_rcp(float v)  { return __builtin_amdgcn_rcpf(v); }

// ---- prefold: b2 = bias * LOG2E (1 MB in d_ws, rewritten every launch) ----
__global__ __launch_bounds__(256) void prefold_kernel(
    const float* __restrict__ bias, float* __restrict__ b2)
{
    const int i = blockIdx.x * 256 + threadIdx.x;   // float4 index
    const float4 b = ((const float4*)bias)[i];
    ((float4*)b2)[i] = make_float4(b.x * LOG2E, b.y * LOG2E, b.z * LOG2E, b.w * LOG2E);
}

__device__ __forceinline__ float wave_reduce_sum(float v) {
    #pragma unroll
    for (int off = 1; off < 64; off <<= 1)
        v += __shfl_xor(v, off, 64);
    return v;
}

// One workgroup per batch element; whole T-recurrence inside the kernel.
// Register discipline (R2/R3 post-mortem): NO manual multi-iteration
// prefetch (spilled at the allocator's 64-reg cap -> 17.5 GB scratch
// traffic). waves_per_eu(4,4) pins the budget to 128 regs for the real
// 1-block/CU occupancy. Loop kept dynamic (#pragma unroll 1) to bound the
// scheduler's live-range window.
template <bool FOLDED>
__global__ __launch_bounds__(BLOCK)
__attribute__((amdgpu_waves_per_eu(4, 4)))
void hmm_forward_kernel(
    const float* __restrict__ x,           // [B, T]
    const float* __restrict__ prior_w,     // [K]
    const float* __restrict__ emission_w,  // [K, 2]
    const float* __restrict__ coeff,       // [K, K]
    const float* __restrict__ bb,          // [K, K] = bias*LOG2E if FOLDED else bias
    float* __restrict__ out)               // [B, K]
{
    __shared__ float post[KDIM];
    __shared__ float em0s[KDIM];
    __shared__ float emds[KDIM];          // em1 - em0
    __shared__ float part[NWAVE][KDIM];   // per-wave pbe partials (32 KB)
    __shared__ float rtmp[NWAVE];
    __shared__ float xs[TDIM];

    const int b    = blockIdx.x;
    const int tid  = threadIdx.x;
    const int lane = tid & 63;
    const int wv   = tid >> 6;
    const int k0   = 4 * lane;            // lane covers k0..k0+3 and k0+256..k0+259

    if (tid < TDIM) xs[tid] = x[b * TDIM + tid];
    if (tid < KDIM) {
        const float w0 = emission_w[2 * tid + 0];
        const float w1 = emission_w[2 * tid + 1];
        const float e0 = 1.0f / (1.0f + fast_exp2((w1 - w0) * LOG2E));
        em0s[tid] = e0;
        emds[tid] = 1.0f - 2.0f * e0;
    }
    __syncthreads();

    // ---- t = 0 ----
    {
        const float x0 = xs[0];
        float v = 0.0f;
        if (tid < KDIM) {
            const float pr = fast_exp2(prior_w[tid] * LOG2E);
            v = pr * fmaf(x0, emds[tid], em0s[tid]);
        }
        float s = wave_reduce_sum(v);
        if (lane == 0) rtmp[wv] = s;
        __syncthreads();
        if (wv == 0) {
            float t2 = (lane < NWAVE) ? rtmp[lane] : 0.0f;
            #pragma unroll
            for (int off = 1; off < NWAVE; off <<= 1)
                t2 += __shfl_xor(t2, off, 64);
            if (lane == 0) rtmp[0] = t2;
        }
        __syncthreads();
        const float rn = fast_rcp(rtmp[0]);
        if (tid < KDIM) post[tid] = v * rn;
        __syncthreads();
    }

    // ---- steps t = 1 .. T-1 ----
    for (int t = 1; t < TDIM; ++t) {
        float acc[8];
        #pragma unroll
        for (int i = 0; i < 8; ++i) acc[i] = 0.0f;

        // wave wv: row pairs (jA = wv+32*i, jB = jA+16), i = 0..15
        const float* cA = coeff + (size_t)wv * KDIM + k0;
        const float* bA = bb    + (size_t)wv * KDIM + k0;
        const float* cB = cA + 16 * KDIM;
        const float* bB = bA + 16 * KDIM;

        #pragma unroll 1
        for (int i = 0; i < 16; ++i) {
            const float4 cA0 = *(const float4*)cA;
            const float4 cA1 = *(const float4*)(cA + 256);
            const float4 cB0 = *(const float4*)cB;
            const float4 cB1 = *(const float4*)(cB + 256);
            const float4 bA0 = *(const float4*)bA;
            const float4 bA1 = *(const float4*)(bA + 256);
            const float4 bB0 = *(const float4*)bB;
            const float4 bB1 = *(const float4*)(bB + 256);
            cA += 32 * KDIM; cB += 32 * KDIM;
            bA += 32 * KDIM; bB += 32 * KDIM;

            const float pA = post[wv + 32 * i];
            const float pB = post[wv + 16 + 32 * i];
            const float pAL = pA * LOG2E;   // hoisted: element = fma + exp2 only
            const float pBL = pB * LOG2E;

            float eA0, eA1, eA2, eA3, eA4, eA5, eA6, eA7;
            float eB0, eB1, eB2, eB3, eB4, eB5, eB6, eB7;
            if (FOLDED) {
                eA0 = fast_exp2(fmaf(pAL, cA0.x, bA0.x));
                eA1 = fast_exp2(fmaf(pAL, cA0.y, bA0.y));
                eA2 = fast_exp2(fmaf(pAL, cA0.z, bA0.z));
                eA3 = fast_exp2(fmaf(pAL, cA0.w, bA0.w));
                eA4 = fast_exp2(fmaf(pAL, cA1.x, bA1.x));
                eA5 = fast_exp2(fmaf(pAL, cA1.y, bA1.y));
                eA6 = fast_exp2(fmaf(pAL, cA1.z, bA1.z));
                eA7 = fast_exp2(fmaf(pAL, cA1.w, bA1.w));
                eB0 = fast_exp2(fmaf(pBL, cB0.x, bB0.x));
                eB1 = fast_exp2(fmaf(pBL, cB0.y, bB0.y));
                eB2 = fast_exp2(fmaf(pBL, cB0.z, bB0.z));
                eB3 = fast_exp2(fmaf(pBL, cB0.w, bB0.w));
                eB4 = fast_exp2(fmaf(pBL, cB1.x, bB1.x));
                eB5 = fast_exp2(fmaf(pBL, cB1.y, bB1.y));
                eB6 = fast_exp2(fmaf(pBL, cB1.z, bB1.z));
                eB7 = fast_exp2(fmaf(pBL, cB1.w, bB1.w));
            } else {
                eA0 = fast_exp2(fmaf(pA, cA0.x, bA0.x) * LOG2E);
                eA1 = fast_exp2(fmaf(pA, cA0.y, bA0.y) * LOG2E);
                eA2 = fast_exp2(fmaf(pA, cA0.z, bA0.z) * LOG2E);
                eA3 = fast_exp2(fmaf(pA, cA0.w, bA0.w) * LOG2E);
                eA4 = fast_exp2(fmaf(pA, cA1.x, bA1.x) * LOG2E);
                eA5 = fast_exp2(fmaf(pA, cA1.y, bA1.y) * LOG2E);
                eA6 = fast_exp2(fmaf(pA, cA1.z, bA1.z) * LOG2E);
                eA7 = fast_exp2(fmaf(pA, cA1.w, bA1.w) * LOG2E);
                eB0 = fast_exp2(fmaf(pB, cB0.x, bB0.x) * LOG2E);
                eB1 = fast_exp2(fmaf(pB, cB0.y, bB0.y) * LOG2E);
                eB2 = fast_exp2(fmaf(pB, cB0.z, bB0.z) * LOG2E);
                eB3 = fast_exp2(fmaf(pB, cB0.w, bB0.w) * LOG2E);
                eB4 = fast_exp2(fmaf(pB, cB1.x, bB1.x) * LOG2E);
                eB5 = fast_exp2(fmaf(pB, cB1.y, bB1.y) * LOG2E);
                eB6 = fast_exp2(fmaf(pB, cB1.z, bB1.z) * LOG2E);
                eB7 = fast_exp2(fmaf(pB, cB1.w, bB1.w) * LOG2E);
            }

            float sA = ((eA0 + eA1) + (eA2 + eA3)) + ((eA4 + eA5) + (eA6 + eA7));
            float sB = ((eB0 + eB1) + (eB2 + eB3)) + ((eB4 + eB5) + (eB6 + eB7));
            #pragma unroll
            for (int off = 1; off < 64; off <<= 1) {   // dual independent chains
                sA += __shfl_xor(sA, off, 64);
                sB += __shfl_xor(sB, off, 64);
            }
            const float scA = pA * fast_rcp(sA);
            const float scB = pB * fast_rcp(sB);

            acc[0] = fmaf(scA, eA0, acc[0]); acc[0] = fmaf(scB, eB0, acc[0]);
            acc[1] = fmaf(scA, eA1, acc[1]); acc[1] = fmaf(scB, eB1, acc[1]);
            acc[2] = fmaf(scA, eA2, acc[2]); acc[2] = fmaf(scB, eB2, acc[2]);
            acc[3] = fmaf(scA, eA3, acc[3]); acc[3] = fmaf(scB, eB3, acc[3]);
            acc[4] = fmaf(scA, eA4, acc[4]); acc[4] = fmaf(scB, eB4, acc[4]);
            acc[5] = fmaf(scA, eA5, acc[5]); acc[5] = fmaf(scB, eB5, acc[5]);
            acc[6] = fmaf(scA, eA6, acc[6]); acc[6] = fmaf(scB, eB6, acc[6]);
            acc[7] = fmaf(scA, eA7, acc[7]); acc[7] = fmaf(scB, eB7, acc[7]);
        }

        *(float4*)(&part[wv][k0])       = make_float4(acc[0], acc[1], acc[2], acc[3]);
        *(float4*)(&part[wv][256 + k0]) = make_float4(acc[4], acc[5], acc[6], acc[7]);
        __syncthreads();

        float v = 0.0f;
        if (tid < KDIM) {
            float pbe = 0.0f;
            #pragma unroll
            for (int w2 = 0; w2 < NWAVE; ++w2) pbe += part[w2][tid];
            v = pbe * fmaf(xs[t], emds[tid], em0s[tid]);
        }
        float s = wave_reduce_sum(v);
        if (lane == 0) rtmp[wv] = s;
        __syncthreads();
        if (wv == 0) {
            float t2 = (lane < NWAVE) ? rtmp[lane] : 0.0f;
            #pragma unroll
            for (int off = 1; off < NWAVE; off <<= 1)
                t2 += __shfl_xor(t2, off, 64);
            if (lane == 0) rtmp[0] = t2;
        }
        __syncthreads();
        const float rn = fast_rcp(rtmp[0]);
        if (tid < KDIM) post[tid] = v * rn;
        __syncthreads();
    }

    if (tid < KDIM) out[b * KDIM + tid] = post[tid];
}

extern "C" void kernel_launch(void* const* d_in, const int* in_sizes, int n_in,
                              void* d_out, int out_size, void* d_ws, size_t ws_size,
                              hipStream_t stream) {
    const float* x          = (const float*)d_in[0];
    const float* prior_w    = (const float*)d_in[1];
    const float* emission_w = (const float*)d_in[2];
    const float* coeff      = (const float*)d_in[3];
    const float* bias       = (const float*)d_in[4];
    float* out              = (float*)d_out;

    const size_t need = (size_t)KDIM * KDIM * sizeof(float);   // 1 MB for b2
    if (ws_size >= need) {
        float* b2 = (float*)d_ws;
        hipLaunchKernelGGL(prefold_kernel, dim3(KDIM * KDIM / 4 / 256), dim3(256),
                           0, stream, bias, b2);
        hipLaunchKernelGGL((hmm_forward_kernel<true>), dim3(BDIM), dim3(BLOCK),
                           0, stream, x, prior_w, emission_w, coeff, b2, out);
    } else {
        hipLaunchKernelGGL((hmm_forward_kernel<false>), dim3(BDIM), dim3(BLOCK),
                           0, stream, x, prior_w, emission_w, coeff, bias, out);
    }
}